// Round 17
// baseline (34.776 us; speedup 1.0000x reference)
//
#include <hip/hip_runtime.h>
#include <hip/hip_bf16.h>

#define B    64
#define T    4096
#define V    64
#define NQ   64      // NGRAN * NGLIMPSE
#define NHID 2048
#define KDIM 4096    // V * NQ
#define FAN  4097    // KDIM + 1 (l_t column)

#define NT     16    // h rows per gemm block
#define SPLITS 16    // K-split across gemm blocks
#define KC     256   // k per block (KDIM/SPLITS)

typedef __attribute__((ext_vector_type(8))) short bf16x8;
typedef __attribute__((ext_vector_type(4))) float f32x4;

static __device__ __forceinline__ short f2bf(float x) {
    union { float f; unsigned u; } c; c.f = x;
    unsigned r = c.u + 0x7fff + ((c.u >> 16) & 1);   // RNE
    return (short)(r >> 16);
}

static __device__ __forceinline__ void load_lds16(const void* g, void* l) {
    __builtin_amdgcn_global_load_lds(
        (const __attribute__((address_space(1))) void*)g,
        (__attribute__((address_space(3))) void*)l, 16, 0, 0);
}

// ---------------------------------------------------------------------------
// Kernel 1: glimpse interpolation + FUSED W fp32->bf16 conversion.
// grid = (B, NQ), block = 64 (lane = v). The W-conversion loads are
// independent and coalesced; they hide under the binary-search dependency
// chain (kernel is latency-bound: 30% occ, 9% VALU, 1.4% HBM).
// Writes g_bf16[b][k] (k=v*NQ+q), Wb[2048][4096] bf16, out2, and zeroes
// the out[] slice for the gemm's atomicAdd.
// ---------------------------------------------------------------------------
__global__ __launch_bounds__(64) void glimpse_kernel(
    const float* __restrict__ vals, const float* __restrict__ time_,
    const int* __restrict__ masks, const float* __restrict__ l_t,
    const float* __restrict__ W, unsigned short* __restrict__ Wb,
    unsigned short* __restrict__ g_bf, float* __restrict__ out2,
    float* __restrict__ out)
{
    const int b = blockIdx.x;
    const int q = blockIdx.y;
    const int v = threadIdx.x;

    if (v < 32) out[(size_t)b * NHID + q * 32 + v] = 0.0f;

    // ---- W conversion side-job: this block owns 2048 consecutive flat
    // elements of Wb[2048][4096] (f = row*4096 + col; src skips l_t col).
    {
        const size_t f0 = ((size_t)b * NQ + q) * 2048;
        #pragma unroll 8
        for (int i = 0; i < 32; ++i) {
            const size_t f = f0 + (size_t)i * 64 + v;
            const int row = (int)(f >> 12);
            const int col = (int)(f & 4095);
            Wb[f] = (unsigned short)f2bf(W[(size_t)row * FAN + col]);
        }
    }

    const float* t = time_ + (size_t)b * T;
    const float tmax = t[T - 1];          // times sorted ascending

    const int   j = q & 31;
    const float s = (q < 32) ? 1.0f : 5.0f;
    const float a = 0.5f * 0.1f * s;      // gwidth*s/2
    const float step = (2.0f * a) / 31.0f;
    float lin = (j == 31) ? a : (-a + step * (float)j);
    const float r = (lin + l_t[b]) * tmax;

    // binary search: p = first index with t[p] > r  (wave-uniform)
    int lo = 0, hi = T;
    while (lo < hi) {
        int mid = (lo + hi) >> 1;
        if (t[mid] > r) hi = mid; else lo = mid + 1;
    }
    const int p = lo;

    const int*   m  = masks + (size_t)b * T * V + v;
    const float* vv = vals  + (size_t)b * T * V + v;

    int i0 = -1;
    for (int i = p - 1; i >= 0; --i) {
        if (m[(size_t)i * V] != 0) { i0 = i; break; }
    }
    int i1 = -1;
    for (int i = p; i < T; ++i) {
        if (m[(size_t)i * V] != 0) { i1 = i; break; }
    }

    float y;
    if (i0 < 0 && i1 < 0) {
        y = 0.0f;
    } else if (i0 < 0) {
        y = vv[(size_t)i1 * V];
    } else if (i1 < 0) {
        y = vv[(size_t)i0 * V];
    } else {
        float t0 = t[i0], t1 = t[i1];
        float v0 = vv[(size_t)i0 * V], v1 = vv[(size_t)i1 * V];
        float den = (t1 > t0) ? (t1 - t0) : 1.0f;
        float w = (r - t0) / den;
        w = fminf(fmaxf(w, 0.0f), 1.0f);
        y = v0 + w * (v1 - v0);
    }

    const int k = v * NQ + q;
    g_bf[(size_t)b * KDIM + k] = (unsigned short)f2bf(y);
    if (k == KDIM / 2) out2[b] = y;             // g[:, 2048], fp32
}

// ---------------------------------------------------------------------------
// Kernel 2: MFMA GEMM, BOTH operands bf16 via global_load_lds + both-sides
// XOR swizzle. LDS 40KB -> 4 blocks/CU, 16 waves/CU (occ 26% -> ~50%).
// grid = (NHID/NT, SPLITS) = (128,16) = 2048 blocks x 256 thr (4 waves).
// Wave w: m-rows [16w,16w+16) x 16 h x 256 k = 8 MFMAs. atomicAdd tail
// (out pre-zeroed by glimpse).
// ---------------------------------------------------------------------------
__global__ __launch_bounds__(256) void gemm_mfma(
    const unsigned short* __restrict__ g_bf, const unsigned short* __restrict__ Wb,
    const float* __restrict__ l_t, const float* __restrict__ W,
    const float* __restrict__ bias, float* __restrict__ out)
{
    __shared__ unsigned short alds[B * KC];     // 32 KB
    __shared__ unsigned short wlds[NT * KC];    // 8 KB
    const int tid  = threadIdx.x;
    const int l    = tid & 63;
    const int w    = tid >> 6;
    const int l15  = l & 15;
    const int lk   = l >> 4;                    // k-group 0..3
    const int hbase = blockIdx.x * NT;
    const int s     = blockIdx.y;
    const int kbase = s * KC;

    // ---- stage A: 32 x 1KB wave-chunks; chunk m covers rows 2m,2m+1.
    // lane l -> LDS position l (linear); source chunk inverse-swizzled so
    // row r's chunk c lands at position c^(r&7).
    #pragma unroll
    for (int i = 0; i < 8; ++i) {
        const int m = w * 8 + i;
        const int r = 2 * m + (l >> 5);
        const int c = (l & 31) ^ (r & 7);       // 16B = 8 bf16 chunk
        load_lds16(g_bf + (size_t)r * KDIM + kbase + c * 8,
                   alds + m * 512);
    }
    // ---- stage W (bf16): 8 x 1KB wave-chunks, same pattern ----
    #pragma unroll
    for (int i = 0; i < 2; ++i) {
        const int m = w * 2 + i;                // 0..7
        const int r = 2 * m + (l >> 5);         // row 0..15
        const int c = (l & 31) ^ (r & 7);
        load_lds16(Wb + (size_t)(hbase + r) * KDIM + kbase + c * 8,
                   wlds + m * 512);
    }
    asm volatile("s_waitcnt vmcnt(0)" ::: "memory");
    __syncthreads();

    f32x4 acc = (f32x4){0.f, 0.f, 0.f, 0.f};
    const int ra = w * 16 + l15;                // A row (b)
    const int rb = l15;                         // W row (h offset)

    #pragma unroll
    for (int ks = 0; ks < 8; ++ks) {
        const int ca = ks * 4 + lk;             // k-chunk of this fragment
        const bf16x8 afrag =
            *(const bf16x8*)(alds + ra * KC + ((ca ^ (ra & 7)) << 3));
        const bf16x8 bfrag =
            *(const bf16x8*)(wlds + rb * KC + ((ca ^ (rb & 7)) << 3));
        acc = __builtin_amdgcn_mfma_f32_16x16x32_bf16(afrag, bfrag, acc, 0, 0, 0);
    }

    // C/D layout: col = lane&15 (h offset), row = (lane>>4)*4 + reg (b offset)
    const int h = hbase + l15;
    #pragma unroll
    for (int rr = 0; rr < 4; ++rr) {
        const int b = w * 16 + lk * 4 + rr;
        float v = acc[rr];
        if (s == 0)
            v += bias[h] + l_t[b] * W[(size_t)h * FAN + KDIM];
        atomicAdd(&out[(size_t)b * NHID + h], v);
    }
}

extern "C" void kernel_launch(void* const* d_in, const int* in_sizes, int n_in,
                              void* d_out, int out_size, void* d_ws, size_t ws_size,
                              hipStream_t stream) {
    const float* vals  = (const float*)d_in[0];
    const float* time_ = (const float*)d_in[1];
    const int*   masks = (const int*)d_in[2];
    // d_in[3] = lengths (all == T, unused)
    const float* l_t   = (const float*)d_in[4];
    const float* W     = (const float*)d_in[5];
    const float* bias  = (const float*)d_in[6];

    float* out  = (float*)d_out;                 // grep [B, NHID]
    float* out2 = out + (size_t)B * NHID;        // g[:, 2048]  [B]
    unsigned short* g_bf = (unsigned short*)d_ws;              // 512 KB
    unsigned short* Wb = (unsigned short*)((char*)d_ws + (1 << 20)); // 16 MB bf16 W

    dim3 g1(B, NQ);
    glimpse_kernel<<<g1, 64, 0, stream>>>(vals, time_, masks, l_t, W, Wb,
                                          g_bf, out2, out);

    dim3 g2(NHID / NT, SPLITS);
    gemm_mfma<<<g2, 256, 0, stream>>>(g_bf, Wb, l_t, W, bias, out);
}